// Round 1
// baseline (134.155 us; speedup 1.0000x reference)
//
#include <hip/hip_runtime.h>
#include <math.h>

// Residual 4-level E8-root VQ.
// Outputs (concat, all float32 in d_out):
//   [0, 8N)          quantized_ste = (qsum + x) - x   (matches jnp rounding)
//   [8N, 12N)        idx_stack[4][N] as float (values 0..239)
//   [12N]            qerr = mean((x - qsum)^2)
//
// Numerics are engineered to match the reference bit-for-bit where possible:
//  - r2[j] == 2.0 exactly for every E8 root; d2 = fl(fl(res2+2) - 2*dot),
//    realized as fmaf(-2, dot, s) (2*dot is exact -> identical rounding).
//  - clip(.,0) dropped: true distances >= 0, and at most ONE root can have
//    rounded d2 <= 0 (roots are >= sqrt(2) apart), so argmin with strict-<
//    scan in reference index order is identical to argmin(clip(d2)).
//  - Type-1 dots (+-r_i +- r_j): exact under ANY summation order (other 6
//    products are exact zeros), so 1 add each.
//  - Type-2 dots: emulate SEQUENTIAL k=0..7 accumulation (BLAS microkernel
//    order) via shared prefix tables (D depth-4, E depth-5) + IEEE negation
//    symmetry fl(-a-b) == -fl(a+b); chain sign tracked at compile time.
//    Sharing computes the IDENTICAL float op sequence once -> bit-exact.
//  - res2: numpy pairwise tree ((q0+q1)+(q2+q3))+((q4+q5)+(q6+q7)).
//  - fp contract OFF so the compiler can't re-fuse r*r into the sum tree.
//
// R1 perf change vs previous version (theory: exposed serial argmin chain):
//  - argmin split into 4 INDEPENDENT chains over contiguous candidate blocks
//    [0,56) [56,112) [112,176) [176,240); each chain scans in increasing
//    index order with strict '<' (keeps first index on rounded-d2 ties);
//    final merge compares later blocks with strict '<' so lower blocks win
//    ties -> globally identical to reference argmin, but 4x chain ILP.
//  - best-update via fminf (v_min_f32): per-candidate cross-iteration
//    dependence is 1 op deep (min chain) instead of cmp->cndmask (2 deep).
//  - E[16] prefix table saves 1 add per Type-2 candidate (112 VALU/level).

__global__ __launch_bounds__(256) void e8_quant_kernel(
    const float* __restrict__ x, const float* __restrict__ roots,
    float* __restrict__ out, float* __restrict__ partials, int nrow) {
#pragma clang fp contract(off)
  __shared__ float lroots[240 * 8];
  __shared__ float wred[4];
  for (int t = threadIdx.x; t < 240 * 8; t += 256) lroots[t] = roots[t];
  __syncthreads();

  const int row = blockIdx.x * 256 + threadIdx.x;
  const bool active = row < nrow;
  float e = 0.f;

  if (active) {
    const float4 xa = *(const float4*)(x + (size_t)row * 8);
    const float4 xb = *(const float4*)(x + (size_t)row * 8 + 4);
    float xr[8] = {xa.x, xa.y, xa.z, xa.w, xb.x, xb.y, xb.z, xb.w};
    float qs[8] = {0.f, 0.f, 0.f, 0.f, 0.f, 0.f, 0.f, 0.f};
    float r[8];
#pragma unroll
    for (int k = 0; k < 8; ++k) r[k] = xr[k];

    float* out_idx = out + (size_t)nrow * 8;

#pragma unroll 1
    for (int lvl = 0; lvl < 4; ++lvl) {
      // res2, numpy pairwise order
      const float q0 = r[0] * r[0], q1 = r[1] * r[1], q2 = r[2] * r[2],
                  q3 = r[3] * r[3], q4 = r[4] * r[4], q5 = r[5] * r[5],
                  q6 = r[6] * r[6], q7 = r[7] * r[7];
      const float res2 = ((q0 + q1) + (q2 + q3)) + ((q4 + q5) + (q6 + q7));
      const float s = res2 + 2.0f;

      // 4 independent argmin chains over contiguous candidate blocks.
      float bst[4] = {3.4028235e38f, 3.4028235e38f, 3.4028235e38f,
                      3.4028235e38f};
      int bix[4] = {0, 56, 112, 176};

      // Strict '<': on rounded-d2 tie the earlier (lower-index) candidate
      // is kept, since each chain scans in increasing index order.
      auto upd = [&](int ch, float d2v, int iv) {
        const bool c = d2v < bst[ch];      // uses OLD best
        bst[ch] = fminf(bst[ch], d2v);     // 1-deep min chain
        bix[ch] = c ? iv : bix[ch];
      };

      // ---- Type-1: 112 roots, pairs (i<j), sign order (++,+-,-+,--) ----
      int ci = 0;
#pragma unroll
      for (int i = 0; i < 8; ++i) {
#pragma unroll
        for (int j = i + 1; j < 8; ++j) {
          const int ch = (ci < 56) ? 0 : 1;  // pair-aligned block split
          const float a = r[i] + r[j];  // dot for (+,+); -(a) for (-,-)
          const float b = r[i] - r[j];  // dot for (+,-); -(b) for (-,+)
          upd(ch, fmaf(-2.f, a, s), ci + 0);
          upd(ch, fmaf(-2.f, b, s), ci + 1);
          upd(ch, fmaf(2.f, b, s), ci + 2);
          upd(ch, fmaf(2.f, a, s), ci + 3);
          ci += 4;
        }
      }

      // ---- Type-2: 128 roots, even-parity sign masks m, increasing m ----
      const float h0 = 0.5f * r[0], h1 = 0.5f * r[1], h2 = 0.5f * r[2],
                  h3 = 0.5f * r[3], h4 = 0.5f * r[4], h5 = 0.5f * r[5],
                  h6 = 0.5f * r[6], h7 = 0.5f * r[7];
      // sequential-prefix tables, stored up-to-sign (sigma = -1 iff bit0 set)
      const float A = h0 + h1, B = h0 - h1;
      const float C0 = A + h2, C1 = A - h2, C2 = B + h2, C3 = B - h2;
      const float D[8] = {C0 + h3, C0 - h3, C1 + h3, C1 - h3,
                          C2 + h3, C2 - h3, C3 + h3, C3 - h3};
      float E[16];
#pragma unroll
      for (int q = 0; q < 8; ++q) {
        E[2 * q] = D[q] + h4;      // depth-5 prefix, '+' h4 (V-space)
        E[2 * q + 1] = D[q] - h4;  // '-' h4
      }
#pragma unroll
      for (int t = 0; t < 128; ++t) {
        // t-th even-parity mask in increasing order
        const int m = (t << 1) | (__popc(t) & 1);
        const int b0 = m & 1, b1 = (m >> 1) & 1, b2 = (m >> 2) & 1,
                  b3 = (m >> 3) & 1;
        // chain value V relates to true prefix by factor sigma = (b0? -1:+1);
        // effective add-sign in V-space for h_k is '+' iff (bit_k == b0).
        const bool Xa = (b0 == b1);
        const int cidx = Xa ? ((b2 == b0) ? 0 : 1) : ((b2 == b0) ? 2 : 3);
        const int di = cidx * 2 + ((b3 == b0) ? 0 : 1);
        const int ei = di * 2 + ((((m >> 4) & 1) == b0) ? 0 : 1);
        float v = E[ei];
        v = (((m >> 5) & 1) == b0) ? (v + h5) : (v - h5);
        v = (((m >> 6) & 1) == b0) ? (v + h6) : (v - h6);
        v = (((m >> 7) & 1) == b0) ? (v + h7) : (v - h7);
        // dot = sigma * v;  d2 = fl(s - 2*dot)
        const float d2v = b0 ? fmaf(2.f, v, s) : fmaf(-2.f, v, s);
        upd((t < 64) ? 2 : 3, d2v, 112 + t);
      }

      // ---- ordered merge: strict '<' keeps the lower block on ties, so
      // the global winner is the first index achieving the global min. ----
      const bool c1 = bst[1] < bst[0];
      const float m01 = c1 ? bst[1] : bst[0];
      const int i01 = c1 ? bix[1] : bix[0];
      const bool c3 = bst[3] < bst[2];
      const float m23 = c3 ? bst[3] : bst[2];
      const int i23 = c3 ? bix[3] : bix[2];
      const int bi = (m23 < m01) ? i23 : i01;

      out_idx[(size_t)lvl * nrow + row] = (float)bi;

      // gather winning root from LDS; update qsum and residual (ref order)
      const float4 ra = *(const float4*)(lroots + bi * 8);
      const float4 rb = *(const float4*)(lroots + bi * 8 + 4);
      qs[0] += ra.x; qs[1] += ra.y; qs[2] += ra.z; qs[3] += ra.w;
      qs[4] += rb.x; qs[5] += rb.y; qs[6] += rb.z; qs[7] += rb.w;
#pragma unroll
      for (int k = 0; k < 8; ++k) r[k] = xr[k] - qs[k];
    }

    // quantized_ste = (qsum + x) - x, left-assoc like the reference
    float o[8];
#pragma unroll
    for (int k = 0; k < 8; ++k) o[k] = (qs[k] + xr[k]) - xr[k];
    *(float4*)(out + (size_t)row * 8) = make_float4(o[0], o[1], o[2], o[3]);
    *(float4*)(out + (size_t)row * 8 + 4) = make_float4(o[4], o[5], o[6], o[7]);

    // qerr partial: sum (x - qsum)^2  (== r after last level)
#pragma unroll
    for (int k = 0; k < 8; ++k) e = fmaf(r[k], r[k], e);
  }

  // block reduction of e -> partials[blockIdx.x]
#pragma unroll
  for (int off = 32; off > 0; off >>= 1) e += __shfl_down(e, off, 64);
  const int lane = threadIdx.x & 63, wv = threadIdx.x >> 6;
  if (lane == 0) wred[wv] = e;
  __syncthreads();
  if (threadIdx.x == 0)
    partials[blockIdx.x] = (wred[0] + wred[1]) + (wred[2] + wred[3]);
}

__global__ __launch_bounds__(256) void qerr_reduce_kernel(
    const float* __restrict__ partials, float* __restrict__ out, int n,
    size_t pos, float scale) {
#pragma clang fp contract(off)
  __shared__ float wred[4];
  float e = 0.f;
  for (int i = threadIdx.x; i < n; i += 256) e += partials[i];
#pragma unroll
  for (int off = 32; off > 0; off >>= 1) e += __shfl_down(e, off, 64);
  const int lane = threadIdx.x & 63, wv = threadIdx.x >> 6;
  if (lane == 0) wred[wv] = e;
  __syncthreads();
  if (threadIdx.x == 0)
    out[pos] = ((wred[0] + wred[1]) + (wred[2] + wred[3])) * scale;
}

extern "C" void kernel_launch(void* const* d_in, const int* in_sizes, int n_in,
                              void* d_out, int out_size, void* d_ws,
                              size_t ws_size, hipStream_t stream) {
  const float* x = (const float*)d_in[0];
  const float* roots = (const float*)d_in[1];
  float* out = (float*)d_out;
  float* partials = (float*)d_ws;

  const int nrow = in_sizes[0] / 8;
  const int nblocks = (nrow + 255) / 256;

  e8_quant_kernel<<<nblocks, 256, 0, stream>>>(x, roots, out, partials, nrow);

  const size_t qerr_pos = (size_t)nrow * 12;
  const float scale = 1.0f / (float)((size_t)nrow * 8);  // 1/2^22, exact
  qerr_reduce_kernel<<<1, 256, 0, stream>>>(partials, out, nblocks, qerr_pos,
                                            scale);
}